// Round 7
// baseline (91.609 us; speedup 1.0000x reference)
//
#include <hip/hip_runtime.h>
#include <math.h>

// Problem constants: B=2, H=W=64, C=64, N=4096, NUM_LEVELS=4, RADIUS=3 -> K=49
// out: (B, N, 4*49*64) f32 = 102,760,448 floats (411 MB)
// Pyramid in d_ws as FP16 (values bounded: |normalized f| <= 1, downsample is
// a convex combination -> fp16 quantization error ~5e-4/level, total ~2e-3
// against a 1.0e-2 threshold). Element offsets (in fp16 units):
//   L0: 2*64*64*64 @ 0        (524288)
//   L1: 2*32*32*64 @ 524288   (131072)
//   L2: 2*16*16*64 @ 655360   ( 32768)
//   L3: 2* 8* 8*64 @ 688128   (  8192)   total 696320 halfs = 1.39 MB
// h4 (4xfp16, 8B) base per level l: (524288 - (524288>>2l))/3

typedef _Float16 h4 __attribute__((ext_vector_type(4)));  // 8 B

__global__ __launch_bounds__(256) void normalize_kernel(
    const float* __restrict__ in, _Float16* __restrict__ out) {
  int gtid = blockIdx.x * 256 + threadIdx.x;
  int wave = gtid >> 6;          // pixel index, 0 .. 8191
  int lane = gtid & 63;          // channel
  float v = in[wave * 64 + lane];
  float ss = v * v;
  #pragma unroll
  for (int m = 32; m >= 1; m >>= 1) ss += __shfl_xor(ss, m);
  out[wave * 64 + lane] = (_Float16)(v / (sqrtf(ss) + 1e-6f));
}

// 2x antialiased bilinear downsample (jax.image.resize semantics):
// output i <- input taps {2i-1..2i+2}, base weights {.25,.75,.75,.25},
// out-of-range taps dropped, weights renormalized. fp16 in/out, f32 math.
__global__ __launch_bounds__(256) void downsample_kernel(
    const _Float16* __restrict__ in, _Float16* __restrict__ out, int Si) {
  int So = Si >> 1;
  int gtid = blockIdx.x * 256 + threadIdx.x;
  int wave = gtid >> 6;
  int lane = gtid & 63;
  int ox = wave % So;
  int t  = wave / So;
  int oy = t % So;
  int b  = t / So;

  int xs[4], ys[4];
  float wx[4], wy[4];
  float bw[4] = {0.25f, 0.75f, 0.75f, 0.25f};
  float sx = 0.f, sy = 0.f;
  #pragma unroll
  for (int tt = 0; tt < 4; tt++) {
    int jx = 2 * ox - 1 + tt;
    bool vx = (jx >= 0) && (jx < Si);
    xs[tt] = vx ? jx : 0;
    wx[tt] = vx ? bw[tt] : 0.f;
    sx += wx[tt];
    int jy = 2 * oy - 1 + tt;
    bool vy = (jy >= 0) && (jy < Si);
    ys[tt] = vy ? jy : 0;
    wy[tt] = vy ? bw[tt] : 0.f;
    sy += wy[tt];
  }
  float ix = 1.f / sx, iy = 1.f / sy;
  #pragma unroll
  for (int tt = 0; tt < 4; tt++) { wx[tt] *= ix; wy[tt] *= iy; }

  float acc = 0.f;
  #pragma unroll
  for (int a = 0; a < 4; a++) {
    const _Float16* rp = in + ((long)(b * Si + ys[a]) * Si) * 64 + lane;
    float row = 0.f;
    #pragma unroll
    for (int tt = 0; tt < 4; tt++) row += wx[tt] * (float)rp[xs[tt] * 64];
    acc += wy[a] * row;
  }
  out[((long)(b * So + oy) * So + ox) * 64 + lane] = (_Float16)acc;
}

// Register dx-walk sampler: one block per bn=(b,n), 448 threads.
// group g = l*7 + dyi; c4 = t&15. Each thread emits 7 float4 outputs (dx
// walk), reusing the previous x1 texel pair as the next x0 pair.
// Pyramid reads are fp16 (8 B per texel per lane), converted to f32.
__global__ __launch_bounds__(448, 4) void corr_sample_reg(
    const _Float16* __restrict__ pyr, const float* __restrict__ coords,
    float* __restrict__ out) {
  unsigned bn = blockIdx.x;  // 0..8191
  unsigned b = bn >> 12;
  int t = threadIdx.x;
  int c4 = t & 15;
  int g = t >> 4;   // 0..27
  int l = g / 7;    // level
  int dyi = g - l * 7;

  int Wl = 64 >> l;
  float sc = 1.0f / (float)(1 << l);  // exact power of two
  float fmx = (float)(Wl - 1);
  unsigned base4 = (524288u - (524288u >> (2 * l))) / 3u;  // h4 units

  float cx = coords[bn * 2 + 0];
  float cy = coords[bn * 2 + 1];
  float cxs = cx * sc, cys = cy * sc;

  // Reference quirk preserved: weights use CLIPPED x1/y1 -> exact zero at edge.
  float y = fminf(fmaxf(cys + (float)(dyi - 3), 0.f), fmx);
  int y0 = (int)floorf(y);
  int y1 = min(y0 + 1, Wl - 1);
  float wy0 = (float)y1 - y;
  float wy1 = y - (float)y0;

  const h4* p4 = (const h4*)pyr;
  unsigned pixb = (unsigned)(b * Wl * Wl);
  unsigned r0 = base4 + ((pixb + (unsigned)(y0 * Wl)) << 4) + (unsigned)c4;
  unsigned r1 = base4 + ((pixb + (unsigned)(y1 * Wl)) << 4) + (unsigned)c4;

  unsigned ob = bn * 3136u + (unsigned)l * 784u + ((unsigned)(dyi * 7) << 4) +
                (unsigned)c4;
  float4* o4 = (float4*)out;

  int px = -1;  // x1 >= 1 always, so -1 never falsely matches
  h4 a0 = (h4)0, a1 = (h4)0;
  #pragma unroll
  for (int dxi = 0; dxi < 7; ++dxi) {
    float x = fminf(fmaxf(cxs + (float)(dxi - 3), 0.f), fmx);
    int x0 = (int)floorf(x);
    int x1 = min(x0 + 1, Wl - 1);
    float wx0 = (float)x1 - x;
    float wx1 = x - (float)x0;

    h4 b0, b1;
    if (x0 == px) {
      b0 = a0; b1 = a1;
    } else {
      b0 = p4[r0 + ((unsigned)x0 << 4)];
      b1 = p4[r1 + ((unsigned)x0 << 4)];
    }
    a0 = p4[r0 + ((unsigned)x1 << 4)];
    a1 = p4[r1 + ((unsigned)x1 << 4)];
    px = x1;

    float w00 = wx0 * wy0, w01 = wx0 * wy1, w10 = wx1 * wy0, w11 = wx1 * wy1;
    float4 r;
    r.x = w00 * (float)b0.x + w01 * (float)b1.x + w10 * (float)a0.x + w11 * (float)a1.x;
    r.y = w00 * (float)b0.y + w01 * (float)b1.y + w10 * (float)a0.y + w11 * (float)a1.y;
    r.z = w00 * (float)b0.z + w01 * (float)b1.z + w10 * (float)a0.z + w11 * (float)a1.z;
    r.w = w00 * (float)b0.w + w01 * (float)b1.w + w10 * (float)a0.w + w11 * (float)a1.w;
    o4[ob + (unsigned)(dxi << 4)] = r;
  }
}

extern "C" void kernel_launch(void* const* d_in, const int* in_sizes, int n_in,
                              void* d_out, int out_size, void* d_ws, size_t ws_size,
                              hipStream_t stream) {
  // d_in[0] = fmap1 (normalized then discarded by the reference)
  const float* fmap2 = (const float*)d_in[1];
  const float* coords = (const float*)d_in[2];
  float* out = (float*)d_out;
  _Float16* pyr = (_Float16*)d_ws;

  normalize_kernel<<<2048, 256, 0, stream>>>(fmap2, pyr);
  downsample_kernel<<<512, 256, 0, stream>>>(pyr,          pyr + 524288, 64);
  downsample_kernel<<<128, 256, 0, stream>>>(pyr + 524288, pyr + 655360, 32);
  downsample_kernel<<< 32, 256, 0, stream>>>(pyr + 655360, pyr + 688128, 16);
  // One block per (b,n): 8192 blocks x 448 threads; no LDS, no barriers.
  corr_sample_reg<<<8192, 448, 0, stream>>>(pyr, coords, out);
}